// Round 9
// baseline (790.902 us; speedup 1.0000x reference)
//
#include <hip/hip_runtime.h>

#define S_LEN  64000
#define B_N    64
#define MCH    8            // steps per wave (serial chain)
#define WPB    8            // waves per block
#define BSTEPS (MCH * WPB)  // 64 steps per block
#define NBLK   (S_LEN / BSTEPS) // 1000 blocks

struct Aff { float m00, m01, m10, m11, v0, v1; };

__device__ __forceinline__ Aff aff_id() {
    Aff r; r.m00 = 1.f; r.m01 = 0.f; r.m10 = 0.f; r.m11 = 1.f; r.v0 = 0.f; r.v1 = 0.f;
    return r;
}

// X ∘ Y : apply Y first, then X
__device__ __forceinline__ Aff aff_comp(const Aff& X, const Aff& Y) {
    Aff r;
    r.m00 = fmaf(X.m00, Y.m00, X.m01 * Y.m10);
    r.m01 = fmaf(X.m00, Y.m01, X.m01 * Y.m11);
    r.m10 = fmaf(X.m10, Y.m00, X.m11 * Y.m10);
    r.m11 = fmaf(X.m10, Y.m01, X.m11 * Y.m11);
    r.v0  = fmaf(X.m00, Y.v0, fmaf(X.m01, Y.v1, X.v0));
    r.v1  = fmaf(X.m10, Y.v0, fmaf(X.m11, Y.v1, X.v1));
    return r;
}

// Per-step transform: state' = A*state + c, A = 2H - I, c = 2*gHBx
__device__ __forceinline__ Aff svf_step(float g, float R, float x) {
    Aff a;
    float T  = 1.0f / fmaf(g, g + R, 1.0f);
    float gT = g * T;
    a.m00 = fmaf(2.0f, T, -1.0f);
    a.m01 = -2.0f * gT;
    a.m10 =  2.0f * gT;
    a.m11 = fmaf(2.0f, fmaf(R, gT, T), -1.0f);
    a.v0  = a.m10 * x;
    a.v1  = g * a.v0;
    return a;
}

// LDS staging, stride 7 floats -> 2 lanes/bank max (free)
__device__ __forceinline__ void aff_store_lds(float* p, const Aff& a) {
    p[0] = a.m00; p[1] = a.m01; p[2] = a.m10; p[3] = a.m11; p[4] = a.v0; p[5] = a.v1;
}
__device__ __forceinline__ Aff aff_load_lds(const float* p) {
    Aff a; a.m00 = p[0]; a.m01 = p[1]; a.m10 = p[2]; a.m11 = p[3]; a.v0 = p[4]; a.v1 = p[5];
    return a;
}
// Packed global Aff: 3 x float2 (coalesced across lanes for fixed block)
__device__ __forceinline__ void aff_store_g(float2* p, const Aff& a) {
    p[0] = make_float2(a.m00, a.m01);
    p[1] = make_float2(a.m10, a.m11);
    p[2] = make_float2(a.v0,  a.v1);
}
__device__ __forceinline__ Aff aff_load_g(const float2* p) {
    float2 x = p[0], y = p[1], z = p[2];
    Aff a; a.m00 = x.x; a.m01 = x.y; a.m10 = y.x; a.m11 = y.y; a.v0 = z.x; a.v1 = z.y;
    return a;
}

// Single-pass: micro -> aggregate publish -> windowed lookback -> inclusive
// publish -> replay. flags: 0=none, 1=aggregate ready, 2=inclusive ready.
__global__ __launch_bounds__(512) void k_lookback(
    const float* __restrict__ audio, const float* __restrict__ g,
    const float* __restrict__ twoR, const float* __restrict__ mix,
    float2* __restrict__ wsAgg, float2* __restrict__ wsInc,
    int* __restrict__ flags, float* __restrict__ out)
{
    __shared__ float micro_lds[WPB * B_N * 7];  // 14.3 KB
    __shared__ float lkb[WPB * B_N * 7];        // 14.3 KB lookback partials
    __shared__ int   lkst[WPB];                 // window status
    __shared__ float tile[BSTEPS * 65];         // 16.6 KB transpose tile

    const int b = threadIdx.x & 63;             // lane = batch
    const int w = threadIdx.x >> 6;             // wave 0..7
    const int p = blockIdx.x;
    const int base_idx = (p * BSTEPS + w * MCH) * B_N + b;

    // ---- Phase 1: load inputs into HELD registers; micro transform ----
    float gv[MCH], Rv[MCH], xv[MCH];
#pragma unroll
    for (int i = 0; i < MCH; ++i) {
        const int idx = base_idx + i * B_N;
        gv[i] = g[idx]; Rv[i] = twoR[idx]; xv[i] = audio[idx];
    }
    Aff acc = aff_id();
#pragma unroll
    for (int i = 0; i < MCH; ++i)
        acc = aff_comp(svf_step(gv[i], Rv[i], xv[i]), acc);
    aff_store_lds(&micro_lds[(w * B_N + b) * 7], acc);
    __syncthreads();

    // ---- Phase 2: wave 0 composes + publishes block aggregate ----
    Aff M;  // valid in wave 0 only
    if (w == 0) {
        M = acc;
#pragma unroll
        for (int j = 1; j < WPB; ++j)
            M = aff_comp(aff_load_lds(&micro_lds[(j * B_N + b) * 7]), M);
        aff_store_g(&wsAgg[(p * B_N + b) * 3], M);
        __threadfence();  // device-scope: aggregate visible before flag
        if (b == 0)
            __hip_atomic_store(&flags[p], 1, __ATOMIC_RELEASE,
                               __HIP_MEMORY_SCOPE_AGENT);
    }

    // ---- Phase 3: windowed lookback -> P = prefix over blocks [0, p) ----
    Aff P = aff_id();
    if (p > 0) {
        int base = p;
        bool done = false;
        while (!done) {
            // wave w examines blocks jj = base-1-(w*8+k), k ascending (descending jj)
            Aff part = aff_id();
            int st = 0;
#pragma unroll 1
            for (int k = 0; k < 8; ++k) {
                const int jj = base - 1 - (w * 8 + k);
                if (jj < 0) { st = 1; break; }
                int f;
                do {
                    f = __hip_atomic_load(&flags[jj], __ATOMIC_ACQUIRE,
                                          __HIP_MEMORY_SCOPE_AGENT);
                    if (f == 0) __builtin_amdgcn_s_sleep(2);
                } while (f == 0);
                const float2* src = (f == 2) ? &wsInc[((long)jj * B_N + b) * 3]
                                             : &wsAgg[((long)jj * B_N + b) * 3];
                part = aff_comp(part, aff_load_g(src));
                if (f == 2) { st = 1; break; }   // absorbed full history
            }
            aff_store_lds(&lkb[(w * B_N + b) * 7], part);
            if (b == 0) lkst[w] = st;
            __syncthreads();
            // combine windows in order (w2=0 nearest to p)
#pragma unroll 1
            for (int w2 = 0; w2 < WPB; ++w2) {
                P = aff_comp(P, aff_load_lds(&lkb[(w2 * B_N + b) * 7]));
                if (lkst[w2]) { done = true; break; }
            }
            __syncthreads();  // lkb safe to overwrite next iteration
            base -= 64;
            if (base <= 0) done = true;  // safety net
        }
    }

    // ---- Phase 4: publish inclusive prefix for successors ----
    if (w == 0) {
        Aff I = aff_comp(M, P);
        aff_store_g(&wsInc[(p * B_N + b) * 3], I);
        __threadfence();
        if (b == 0)
            __hip_atomic_store(&flags[p], 2, __ATOMIC_RELEASE,
                               __HIP_MEMORY_SCOPE_AGENT);
    }

    // ---- Phase 5: per-wave entry state + 8-step replay from held regs ----
    Aff Pw = P;
    for (int j = 0; j < w; ++j)
        Pw = aff_comp(aff_load_lds(&micro_lds[(j * B_N + b) * 7]), Pw);
    float s0 = Pw.m00 + Pw.m01 + Pw.v0;   // apply to state0 = (1,1)
    float s1 = Pw.m10 + Pw.m11 + Pw.v1;

#pragma unroll
    for (int i = 0; i < MCH; ++i) {
        const int idx = base_idx + i * B_N;
        float m0 = mix[idx * 3], m1 = mix[idx * 3 + 1], m2 = mix[idx * 3 + 2];
        float gg = gv[i], R = Rv[i], x = xv[i];
        float T  = 1.0f / fmaf(gg, gg + R, 1.0f);
        float gT = gg * T;
        float b0 = gT * x;
        float b1 = gg * b0;
        float Y0 = fmaf(T, s0, fmaf(-gT, s1, b0));
        float Y1 = fmaf(gT, s0, fmaf(fmaf(R, gT, T), s1, b1));
        s0 = fmaf(2.0f, Y0, -s0);
        s1 = fmaf(2.0f, Y1, -s1);
        float yh = x - fmaf(R, Y0, Y1);
        float y  = fmaf(R * m0, Y0, fmaf(m1, Y1, m2 * yh));
        tile[(w * MCH + i) * 65 + b] = y;
    }
    __syncthreads();

    // out[r][p*64 + col]: 64-lane contiguous 256 B stores; LDS reads
    // stride-65 -> 2 lanes/bank (free)
    const int col = threadIdx.x & 63;
    const int r0  = threadIdx.x >> 6;
    const int colbase = p * BSTEPS;
#pragma unroll
    for (int r = r0; r < B_N; r += WPB)
        out[r * S_LEN + colbase + col] = tile[col * 65 + r];
}

extern "C" void kernel_launch(void* const* d_in, const int* in_sizes, int n_in,
                              void* d_out, int out_size, void* d_ws, size_t ws_size,
                              hipStream_t stream)
{
    const float* audio = (const float*)d_in[0];
    const float* g     = (const float*)d_in[1];
    const float* twoR  = (const float*)d_in[2];
    const float* mix   = (const float*)d_in[3];
    float* out = (float*)d_out;

    float2* wsAgg = (float2*)d_ws;                  // NBLK*64*3 float2 (1.54 MB)
    float2* wsInc = wsAgg + (long)NBLK * B_N * 3;   // NBLK*64*3 float2 (1.54 MB)
    int*    flags = (int*)(wsInc + (long)NBLK * B_N * 3);  // NBLK ints (4 KB)

    // flags must be zero at kernel start on EVERY call (graph replays too)
    hipMemsetAsync(flags, 0, NBLK * sizeof(int), stream);

    k_lookback<<<dim3(NBLK), dim3(512), 0, stream>>>(
        audio, g, twoR, mix, wsAgg, wsInc, flags, out);
}

// Round 10
// 37.083 us; speedup vs baseline: 21.3278x; 21.3278x over previous
//
#include <hip/hip_runtime.h>

#define S_LEN  64000
#define B_N    64
#define MCH    8            // steps per micro-chunk (one wave's serial chain)
#define WPB    8            // waves per block (micros per macro)
#define BSTEPS (MCH * WPB)  // 64 steps per block / macro
#define NBLK   (S_LEN / BSTEPS) // 1000 macro chunks
#define SC_T   1024         // scan threads: one macro per thread (>= NBLK)

struct Aff { float m00, m01, m10, m11, v0, v1; };

__device__ __forceinline__ Aff aff_id() {
    Aff r; r.m00 = 1.f; r.m01 = 0.f; r.m10 = 0.f; r.m11 = 1.f; r.v0 = 0.f; r.v1 = 0.f;
    return r;
}

// X ∘ Y : apply Y first, then X
__device__ __forceinline__ Aff aff_comp(const Aff& X, const Aff& Y) {
    Aff r;
    r.m00 = fmaf(X.m00, Y.m00, X.m01 * Y.m10);
    r.m01 = fmaf(X.m00, Y.m01, X.m01 * Y.m11);
    r.m10 = fmaf(X.m10, Y.m00, X.m11 * Y.m10);
    r.m11 = fmaf(X.m10, Y.m01, X.m11 * Y.m11);
    r.v0  = fmaf(X.m00, Y.v0, fmaf(X.m01, Y.v1, X.v0));
    r.v1  = fmaf(X.m10, Y.v0, fmaf(X.m11, Y.v1, X.v1));
    return r;
}

// Per-step transform: state' = A*state + c, A = 2H - I, c = 2*gHBx
__device__ __forceinline__ Aff svf_step(float g, float R, float x) {
    Aff a;
    float T  = 1.0f / fmaf(g, g + R, 1.0f);
    float gT = g * T;
    a.m00 = fmaf(2.0f, T, -1.0f);
    a.m01 = -2.0f * gT;
    a.m10 =  2.0f * gT;
    a.m11 = fmaf(2.0f, fmaf(R, gT, T), -1.0f);
    a.v0  = a.m10 * x;
    a.v1  = g * a.v0;
    return a;
}

// LDS staging, stride 7 floats per (micro, batch) -> 2 lanes/bank max (free)
__device__ __forceinline__ void aff_store_lds(float* p, const Aff& a) {
    p[0] = a.m00; p[1] = a.m01; p[2] = a.m10; p[3] = a.m11; p[4] = a.v0; p[5] = a.v1;
}
__device__ __forceinline__ Aff aff_load_lds(const float* p) {
    Aff a; a.m00 = p[0]; a.m01 = p[1]; a.m10 = p[2]; a.m11 = p[3]; a.v0 = p[4]; a.v1 = p[5];
    return a;
}
// Packed global Aff: 2 x float4 (32 B, 16-B aligned) at entry index e*2
__device__ __forceinline__ void aff_store_g4(float4* p, const Aff& a) {
    p[0] = make_float4(a.m00, a.m01, a.m10, a.m11);
    p[1] = make_float4(a.v0,  a.v1,  0.f,   0.f);
}
__device__ __forceinline__ Aff aff_load_g4(const float4* p) {
    float4 x = p[0], y = p[1];
    Aff a; a.m00 = x.x; a.m01 = x.y; a.m10 = x.z; a.m11 = x.w; a.v0 = y.x; a.v1 = y.y;
    return a;
}

// Pass 1: wave w composes 8-step micro transform; block composes its 8
// micros (64 steps) into one macro transform via LDS. Lane = batch.
// wsMac layout: [batch][macro] (scan-side coalesced; writes scattered).
__global__ __launch_bounds__(512, 4) void k_macro(
    const float* __restrict__ audio, const float* __restrict__ g,
    const float* __restrict__ twoR, float4* __restrict__ wsMac)
{
    __shared__ float affs[WPB * B_N * 7];
    const int b   = threadIdx.x & 63;
    const int w   = threadIdx.x >> 6;
    const int blk = blockIdx.x;
    const int base = (blk * BSTEPS + w * MCH) * B_N + b;

    Aff acc = aff_id();
#pragma unroll
    for (int i = 0; i < MCH; ++i) {
        const int idx = base + i * B_N;
        acc = aff_comp(svf_step(g[idx], twoR[idx], audio[idx]), acc);
    }
    aff_store_lds(&affs[(w * B_N + b) * 7], acc);
    __syncthreads();

    if (w == 0) {
        Aff M = acc;  // micro 0 (this wave's own)
#pragma unroll
        for (int j = 1; j < WPB; ++j) {
            Aff A = aff_load_lds(&affs[(j * B_N + b) * 7]);
            M = aff_comp(A, M);
        }
        aff_store_g4(&wsMac[((long)b * NBLK + blk) * 2], M);
    }
}

// Pass 2: one block (1024 threads) per batch; thread t owns macro t.
// Loads are CONTIGUOUS (block b reads wsMac[b*NBLK .. b*NBLK+999], 32 KB).
// Wave-inclusive shuffle scan -> wave 0 scans the 16 wave totals ->
// combine -> emit per-macro entry state.
__global__ __launch_bounds__(SC_T, 2) void k_scan(
    const float4* __restrict__ wsMac, float2* __restrict__ sIn)
{
    const int b    = blockIdx.x;   // batch
    const int t    = threadIdx.x;  // macro index
    const int lane = t & 63;
    const int wave = t >> 6;       // 0..15

    Aff m = (t < NBLK) ? aff_load_g4(&wsMac[((long)b * NBLK + t) * 2]) : aff_id();

    // wave-inclusive Hillis-Steele scan
    Aff acc = m;
#pragma unroll
    for (int d = 1; d < 64; d <<= 1) {
        Aff o;
        o.m00 = __shfl_up(acc.m00, (unsigned)d, 64);
        o.m01 = __shfl_up(acc.m01, (unsigned)d, 64);
        o.m10 = __shfl_up(acc.m10, (unsigned)d, 64);
        o.m11 = __shfl_up(acc.m11, (unsigned)d, 64);
        o.v0  = __shfl_up(acc.v0,  (unsigned)d, 64);
        o.v1  = __shfl_up(acc.v1,  (unsigned)d, 64);
        if (lane >= d) acc = aff_comp(acc, o);
    }

    __shared__ Aff wt[SC_T / 64];
    if (lane == 63) wt[wave] = acc;
    __syncthreads();

    // wave 0: inclusive scan of the 16 wave totals (lanes 0..15)
    if (wave == 0 && lane < 16) {
        Aff a = wt[lane];
#pragma unroll
        for (int d = 1; d < 16; d <<= 1) {
            Aff o;
            o.m00 = __shfl_up(a.m00, (unsigned)d, 64);
            o.m01 = __shfl_up(a.m01, (unsigned)d, 64);
            o.m10 = __shfl_up(a.m10, (unsigned)d, 64);
            o.m11 = __shfl_up(a.m11, (unsigned)d, 64);
            o.v0  = __shfl_up(a.v0,  (unsigned)d, 64);
            o.v1  = __shfl_up(a.v1,  (unsigned)d, 64);
            if (lane >= d) a = aff_comp(a, o);
        }
        wt[lane] = a;
    }
    __syncthreads();

    if (t < NBLK) {
        // exclusive within wave
        Aff E;
        E.m00 = __shfl_up(acc.m00, 1u, 64);
        E.m01 = __shfl_up(acc.m01, 1u, 64);
        E.m10 = __shfl_up(acc.m10, 1u, 64);
        E.m11 = __shfl_up(acc.m11, 1u, 64);
        E.v0  = __shfl_up(acc.v0,  1u, 64);
        E.v1  = __shfl_up(acc.v1,  1u, 64);
        if (lane == 0) E = aff_id();
        if (wave > 0) E = aff_comp(E, wt[wave - 1]);

        // entry state of macro t: E applied to s0 = (1,1)
        float e0 = E.m00 + E.m01 + E.v0;
        float e1 = E.m10 + E.m11 + E.v1;
        sIn[t * B_N + b] = make_float2(e0, e1);   // scatter-write, hidden
    }
}

// Pass 3: wave w recomputes its micro transform, block shares micros via
// LDS, wave composes its within-block prefix -> exact entry state, then
// replays only 8 steps. Output transposed through padded LDS tile.
__global__ __launch_bounds__(512, 4) void k_replay(
    const float* __restrict__ audio, const float* __restrict__ g,
    const float* __restrict__ twoR, const float* __restrict__ mix,
    const float2* __restrict__ sIn, float* __restrict__ out)
{
    __shared__ float lds[BSTEPS * 65];  // reused: first WPB*64*7 = Aff staging
    const int b   = threadIdx.x & 63;
    const int w   = threadIdx.x >> 6;
    const int blk = blockIdx.x;
    const int base = (blk * BSTEPS + w * MCH) * B_N + b;

    // load this wave's 8 steps of inputs (all independent -> deep in flight)
    const float3* mix3 = (const float3*)mix;
    float gv[MCH], Rv[MCH], xv[MCH];
    float3 mv[MCH];
#pragma unroll
    for (int i = 0; i < MCH; ++i) {
        const int idx = base + i * B_N;
        gv[i] = g[idx]; Rv[i] = twoR[idx]; xv[i] = audio[idx];
        mv[i] = mix3[idx];                      // one dwordx3 per step
    }

    // micro transform for this wave
    Aff acc = aff_id();
#pragma unroll
    for (int i = 0; i < MCH; ++i)
        acc = aff_comp(svf_step(gv[i], Rv[i], xv[i]), acc);
    aff_store_lds(&lds[(w * B_N + b) * 7], acc);
    __syncthreads();

    // entry state: within-block exclusive prefix applied to macro entry
    float2 sm = sIn[blk * B_N + b];             // coalesced
    Aff P = aff_id();
    for (int j = 0; j < w; ++j) {
        Aff A = aff_load_lds(&lds[(j * B_N + b) * 7]);
        P = aff_comp(A, P);
    }
    float s0 = fmaf(P.m00, sm.x, fmaf(P.m01, sm.y, P.v0));
    float s1 = fmaf(P.m10, sm.x, fmaf(P.m11, sm.y, P.v1));
    __syncthreads();  // prefix reads done before tile overwrites staging

    // replay 8 steps, write y into transpose tile
#pragma unroll
    for (int i = 0; i < MCH; ++i) {
        float gg = gv[i], R = Rv[i], x = xv[i];
        float T  = 1.0f / fmaf(gg, gg + R, 1.0f);
        float gT = gg * T;
        float b0 = gT * x;
        float b1 = gg * b0;
        float Y0 = fmaf(T, s0, fmaf(-gT, s1, b0));
        float Y1 = fmaf(gT, s0, fmaf(fmaf(R, gT, T), s1, b1));
        s0 = fmaf(2.0f, Y0, -s0);
        s1 = fmaf(2.0f, Y1, -s1);

        float yh = x - fmaf(R, Y0, Y1);
        float y  = fmaf(R * mv[i].x, Y0, fmaf(mv[i].y, Y1, mv[i].z * yh));

        lds[(w * MCH + i) * 65 + b] = y;
    }
    __syncthreads();

    // out[r][blk*64 + col]: 64-lane contiguous 256 B stores; LDS reads
    // stride-65 -> 2-way max (free)
    const int col = threadIdx.x & 63;
    const int r0  = threadIdx.x >> 6;
    const int colbase = blk * BSTEPS;
#pragma unroll
    for (int r = r0; r < B_N; r += WPB) {
        out[r * S_LEN + colbase + col] = lds[col * 65 + r];
    }
}

extern "C" void kernel_launch(void* const* d_in, const int* in_sizes, int n_in,
                              void* d_out, int out_size, void* d_ws, size_t ws_size,
                              hipStream_t stream)
{
    const float* audio = (const float*)d_in[0];
    const float* g     = (const float*)d_in[1];
    const float* twoR  = (const float*)d_in[2];
    const float* mix   = (const float*)d_in[3];
    float* out = (float*)d_out;

    float4* wsMac = (float4*)d_ws;                       // 64*NBLK*2 float4 (2 MB)
    float2* sIn   = (float2*)(wsMac + (long)B_N * NBLK * 2); // NBLK*64 float2 (0.5 MB)

    k_macro <<<dim3(NBLK), dim3(512), 0, stream>>>(audio, g, twoR, wsMac);
    k_scan  <<<dim3(B_N), dim3(SC_T), 0, stream>>>(wsMac, sIn);
    k_replay<<<dim3(NBLK), dim3(512), 0, stream>>>(audio, g, twoR, mix, sIn, out);
}